// Round 1
// baseline (1074.202 us; speedup 1.0000x reference)
//
#include <hip/hip_runtime.h>

#define NN 50000
#define NE 800000
#define NG 64
#define IN_DIM 128
#define HID4 256
#define OUT_DIM 256
#define EPSF 1e-5f

// ---------------- degree / norms / CSR build ----------------

__global__ void deg_kernel(const int* __restrict__ src, const int* __restrict__ dst,
                           int* __restrict__ dout, int* __restrict__ din, int E) {
  int e = blockIdx.x * 256 + threadIdx.x;
  if (e < E) {
    atomicAdd(&dout[src[e]], 1);
    atomicAdd(&din[dst[e]], 1);
  }
}

__global__ void norms_kernel(const int* __restrict__ dout, const int* __restrict__ din,
                             float* __restrict__ onorm, float* __restrict__ inorm, int n) {
  int v = blockIdx.x * 256 + threadIdx.x;
  if (v < n) {
    int a = dout[v] > 1 ? dout[v] : 1;
    int b = din[v] > 1 ? din[v] : 1;
    onorm[v] = rsqrtf((float)a);
    inorm[v] = rsqrtf((float)b);
  }
}

// single-block exclusive scan of in-degrees -> row_ptr (n=50000, one-time cost)
__global__ void __launch_bounds__(1024) scan_kernel(const int* __restrict__ din,
                                                    int* __restrict__ rp, int n) {
  __shared__ int sums[1024];
  __shared__ int offs[1024];
  int tid = threadIdx.x;
  int chunk = (n + 1023) / 1024;
  int s0 = tid * chunk;
  int s1 = s0 + chunk; if (s1 > n) s1 = n;
  int s = 0;
  for (int i = s0; i < s1; i++) s += din[i];
  sums[tid] = s;
  __syncthreads();
  if (tid == 0) {
    int acc = 0;
    for (int i = 0; i < 1024; i++) { offs[i] = acc; acc += sums[i]; }
    rp[n] = acc;
  }
  __syncthreads();
  int acc = offs[tid];
  for (int i = s0; i < s1; i++) { rp[i] = acc; acc += din[i]; }
}

// scatter edges into dst-grouped CSR; fold w_e * out_norm[src] into edge weight
__global__ void fill_kernel(const int* __restrict__ src, const int* __restrict__ dst,
                            const float* __restrict__ w, const float* __restrict__ onorm,
                            const int* __restrict__ rp, int* __restrict__ cursor,
                            int* __restrict__ col, float* __restrict__ wse, int E) {
  int e = blockIdx.x * 256 + threadIdx.x;
  if (e < E) {
    int d = dst[e];
    int pos = rp[d] + atomicAdd(&cursor[d], 1);
    int s = src[e];
    col[pos] = s;
    wse[pos] = w[e] * onorm[s];
  }
}

// ---------------- SpMM: one block per dst node, thread per feature ----------------
// mode 0: plain store; mode 1: relu(acc * in_norm[v])
__global__ void spmm_kernel(const float* __restrict__ feat, int ldf,
                            const int* __restrict__ rp, const int* __restrict__ col,
                            const float* __restrict__ wse,
                            float* __restrict__ out, int ldo,
                            const float* __restrict__ inorm, int mode) {
  int v = blockIdx.x;
  int f = threadIdx.x;
  int beg = rp[v], end = rp[v + 1];
  float acc = 0.f;
  int e = beg;
  for (; e + 1 < end; e += 2) {
    int s0 = col[e], s1 = col[e + 1];
    float w0 = wse[e], w1 = wse[e + 1];
    float f0 = feat[(size_t)s0 * ldf + f];
    float f1 = feat[(size_t)s1 * ldf + f];
    acc += w0 * f0 + w1 * f1;
  }
  if (e < end) {
    acc += wse[e] * feat[(size_t)col[e] * ldf + f];
  }
  if (mode == 1) {
    acc *= inorm[v];
    acc = acc > 0.f ? acc : 0.f;
  }
  out[(size_t)v * ldo + f] = acc;
}

// ---------------- SGEMM: C[M,256] = A[M,K] @ B[K,256], fused epilogue ----------------
// BM=64, BN=256(full), BK=32, 256 threads, 8x8 micro-tile.
// mode 0: plain; mode 1: relu(val * inorm[row])
#define BM 64
#define BK 32
__global__ void __launch_bounds__(256) gemm_kernel(const float* __restrict__ A, int lda,
                                                   const float* __restrict__ B,
                                                   float* __restrict__ C, int ldc,
                                                   int M, int K,
                                                   const float* __restrict__ inorm, int mode) {
  __shared__ float As[BK][BM + 4];    // [32][68], transposed A tile (k-major)
  __shared__ float Bs[BK][256 + 4];   // [32][260]
  int tid = threadIdx.x;
  int m0 = blockIdx.x * BM;
  int tx = tid & 31;       // 32 col groups of 8
  int ty = tid >> 5;       // 8 row groups of 8
  float acc[8][8];
#pragma unroll
  for (int i = 0; i < 8; i++)
#pragma unroll
    for (int j = 0; j < 8; j++) acc[i][j] = 0.f;

  for (int k0 = 0; k0 < K; k0 += BK) {
    // load A tile 64x32 (512 float4, 2 per thread), store transposed
#pragma unroll
    for (int i = 0; i < 2; i++) {
      int idx4 = tid + i * 256;       // 0..511
      int r = idx4 >> 3;              // 0..63
      int c4 = idx4 & 7;              // 0..7
      int gm = m0 + r;
      float4 v = make_float4(0.f, 0.f, 0.f, 0.f);
      if (gm < M) v = *(const float4*)&A[(size_t)gm * lda + k0 + c4 * 4];
      As[c4 * 4 + 0][r] = v.x;
      As[c4 * 4 + 1][r] = v.y;
      As[c4 * 4 + 2][r] = v.z;
      As[c4 * 4 + 3][r] = v.w;
    }
    // load B tile 32x256 (2048 float4, 8 per thread)
#pragma unroll
    for (int i = 0; i < 8; i++) {
      int idx4 = tid + i * 256;       // 0..2047
      int r = idx4 >> 6;              // 0..31
      int c4 = idx4 & 63;             // 0..63
      float4 v = *(const float4*)&B[(size_t)(k0 + r) * 256 + c4 * 4];
      *(float4*)&Bs[r][c4 * 4] = v;
    }
    __syncthreads();
#pragma unroll
    for (int kk = 0; kk < BK; kk++) {
      float4 a0 = *(const float4*)&As[kk][ty * 8];
      float4 a1 = *(const float4*)&As[kk][ty * 8 + 4];
      float4 b0 = *(const float4*)&Bs[kk][tx * 8];
      float4 b1 = *(const float4*)&Bs[kk][tx * 8 + 4];
      float a[8] = {a0.x, a0.y, a0.z, a0.w, a1.x, a1.y, a1.z, a1.w};
      float b[8] = {b0.x, b0.y, b0.z, b0.w, b1.x, b1.y, b1.z, b1.w};
#pragma unroll
      for (int i = 0; i < 8; i++)
#pragma unroll
        for (int j = 0; j < 8; j++) acc[i][j] += a[i] * b[j];
    }
    __syncthreads();
  }
  // epilogue
#pragma unroll
  for (int i = 0; i < 8; i++) {
    int gm = m0 + ty * 8 + i;
    if (gm >= M) continue;
    float s = 1.f;
    if (mode == 1) s = inorm[gm];
#pragma unroll
    for (int j2 = 0; j2 < 2; j2++) {
      float4 v;
      float* p = &acc[i][j2 * 4];
      v.x = p[0]; v.y = p[1]; v.z = p[2]; v.w = p[3];
      if (mode == 1) {
        v.x = fmaxf(v.x * s, 0.f); v.y = fmaxf(v.y * s, 0.f);
        v.z = fmaxf(v.z * s, 0.f); v.w = fmaxf(v.w * s, 0.f);
      }
      *(float4*)&C[(size_t)gm * ldc + tx * 8 + j2 * 4] = v;
    }
  }
}

// ---------------- LayerNorm + relu over 256-wide rows (in place) ----------------
__global__ void ln_relu_kernel(float* __restrict__ h, int ld,
                               const float* __restrict__ gamma,
                               const float* __restrict__ beta) {
  int v = blockIdx.x;
  int f = threadIdx.x;   // 256
  float val = h[(size_t)v * ld + f];
  float s = val, q = val * val;
#pragma unroll
  for (int off = 32; off > 0; off >>= 1) {
    s += __shfl_down(s, off);
    q += __shfl_down(q, off);
  }
  __shared__ float ws_[5], wq_[5];
  int wave = f >> 6, lane = f & 63;
  if (lane == 0) { ws_[wave] = s; wq_[wave] = q; }
  __syncthreads();
  if (f == 0) {
    float S = 0, Q = 0;
    for (int i = 0; i < 4; i++) { S += ws_[i]; Q += wq_[i]; }
    ws_[4] = S; wq_[4] = Q;
  }
  __syncthreads();
  float mean = ws_[4] * (1.f / 256.f);
  float var = wq_[4] * (1.f / 256.f) - mean * mean;
  float y = (val - mean) * rsqrtf(var + EPSF) * gamma[f] + beta[f];
  h[(size_t)v * ld + f] = y > 0.f ? y : 0.f;
}

// ---------------- per-graph readout (graph_ids sorted) ----------------
__global__ void readout_kernel(const float* __restrict__ x3, const int* __restrict__ gid,
                               float* __restrict__ out, int n) {
  int g = blockIdx.x;
  int part = blockIdx.y;        // 8 parts
  int f = threadIdx.x;          // 256
  // lower_bound(g)
  int lo = 0, hi = n;
  while (lo < hi) { int mid = (lo + hi) >> 1; if (gid[mid] < g) lo = mid + 1; else hi = mid; }
  int s = lo;
  // lower_bound(g+1)
  lo = s; hi = n;
  while (lo < hi) { int mid = (lo + hi) >> 1; if (gid[mid] < g + 1) lo = mid + 1; else hi = mid; }
  int e = lo;
  int len = e - s;
  if (len <= 0) return;
  int chunk = (len + 7) / 8;
  int cs = s + part * chunk;
  int ce = cs + chunk; if (ce > e) ce = e;
  if (cs >= ce) return;
  float acc = 0.f;
  for (int v = cs; v < ce; v++) acc += x3[(size_t)v * 256 + f];
  atomicAdd(&out[g * 256 + f], acc);
}

// ---------------- launch ----------------

extern "C" void kernel_launch(void* const* d_in, const int* in_sizes, int n_in,
                              void* d_out, int out_size, void* d_ws, size_t ws_size,
                              hipStream_t stream) {
  const float* x     = (const float*)d_in[0];
  const float* w     = (const float*)d_in[1];
  const float* W1    = (const float*)d_in[2];
  const float* Wfc   = (const float*)d_in[3];
  const float* gamma = (const float*)d_in[4];
  const float* beta  = (const float*)d_in[5];
  const float* W2    = (const float*)d_in[6];
  const float* W3    = (const float*)d_in[7];
  const int*   src   = (const int*)d_in[8];
  const int*   dst   = (const int*)d_in[9];
  const int*   gid   = (const int*)d_in[10];
  float* out = (float*)d_out;

  const int N = NN, E = NE;

  // workspace layout (all 256B-aligned)
  char* p = (char*)d_ws;
  auto alloc = [&](size_t bytes) {
    char* r = p;
    p += (bytes + 255) & ~(size_t)255;
    return r;
  };
  int*   deg_out = (int*)alloc((size_t)N * 4);
  int*   deg_in  = (int*)alloc((size_t)N * 4);
  float* onorm   = (float*)alloc((size_t)N * 4);
  float* inorm   = (float*)alloc((size_t)N * 4);
  int*   row_ptr = (int*)alloc((size_t)(N + 1) * 4);
  int*   cursor  = (int*)alloc((size_t)N * 4);
  int*   col     = (int*)alloc((size_t)E * 4);
  float* wse     = (float*)alloc((size_t)E * 4);
  float* bufA    = (float*)alloc((size_t)N * 512 * 4);  // x1 | f1 concat
  float* bufB    = (float*)alloc((size_t)N * 256 * 4);  // aggX -> y2 -> agg_x2
  float* bufC    = (float*)alloc((size_t)N * 256 * 4);  // x2 -> x3

  hipMemsetAsync(deg_out, 0, (size_t)N * 4, stream);
  hipMemsetAsync(deg_in, 0, (size_t)N * 4, stream);
  hipMemsetAsync(cursor, 0, (size_t)N * 4, stream);
  hipMemsetAsync(out, 0, (size_t)NG * 256 * 4, stream);

  deg_kernel<<<(E + 255) / 256, 256, 0, stream>>>(src, dst, deg_out, deg_in, E);
  norms_kernel<<<(N + 255) / 256, 256, 0, stream>>>(deg_out, deg_in, onorm, inorm, N);
  scan_kernel<<<1, 1024, 0, stream>>>(deg_in, row_ptr, N);
  fill_kernel<<<(E + 255) / 256, 256, 0, stream>>>(src, dst, w, onorm, row_ptr, cursor,
                                                   col, wse, E);

  int gm_blocks = (N + BM - 1) / BM;   // 782

  // conv1 aggregate: aggX[v] = sum wse * x[src]  -> bufB (ld 256, first 128 cols)
  spmm_kernel<<<N, 128, 0, stream>>>(x, 128, row_ptr, col, wse, bufB, 256, inorm, 0);
  // x1 = relu((aggX @ W1) * inorm) -> bufA[:, 0:256]
  gemm_kernel<<<gm_blocks, 256, 0, stream>>>(bufB, 256, W1, bufA, 512, N, 128, inorm, 1);
  // f1_pre = x @ Wfc -> bufA[:, 256:512]
  gemm_kernel<<<gm_blocks, 256, 0, stream>>>(x, 128, Wfc, bufA + 256, 512, N, 128, inorm, 0);
  // f1 = relu(LN(f1_pre)) in place
  ln_relu_kernel<<<N, 256, 0, stream>>>(bufA + 256, 512, gamma, beta);
  // y2 = x1f1 @ W2 -> bufB (overwrites aggX, done with it)
  gemm_kernel<<<gm_blocks, 256, 0, stream>>>(bufA, 512, W2, bufB, 256, N, 512, inorm, 0);
  // x2 = relu(inorm * agg(y2)) -> bufC
  spmm_kernel<<<N, 256, 0, stream>>>(bufB, 256, row_ptr, col, wse, bufC, 256, inorm, 1);
  // agg_x2 = agg(x2) -> bufB
  spmm_kernel<<<N, 256, 0, stream>>>(bufC, 256, row_ptr, col, wse, bufB, 256, inorm, 0);
  // x3 = relu((agg_x2 @ W3) * inorm) -> bufC
  gemm_kernel<<<gm_blocks, 256, 0, stream>>>(bufB, 256, W3, bufC, 256, N, 256, inorm, 1);
  // readout
  readout_kernel<<<dim3(NG, 8), 256, 0, stream>>>(bufC, gid, out, N);
}

// Round 2
// 649.412 us; speedup vs baseline: 1.6541x; 1.6541x over previous
//
#include <hip/hip_runtime.h>

#define NN 50000
#define NE 800000
#define NG 64
#define EPSF 1e-5f

typedef __bf16 bf16x8 __attribute__((ext_vector_type(8)));
typedef float f32x4 __attribute__((ext_vector_type(4)));

__device__ __forceinline__ unsigned short f2bf(float f) {
  unsigned u = __builtin_bit_cast(unsigned, f);
  u += 0x7fff + ((u >> 16) & 1);   // RNE (finite values only here)
  return (unsigned short)(u >> 16);
}
__device__ __forceinline__ float bf_lo(unsigned u) {
  return __builtin_bit_cast(float, u << 16);
}
__device__ __forceinline__ float bf_hi(unsigned u) {
  return __builtin_bit_cast(float, u & 0xffff0000u);
}

// ---------------- degree / norms / CSR build ----------------

__global__ void deg_kernel(const int* __restrict__ src, const int* __restrict__ dst,
                           int* __restrict__ dout, int* __restrict__ din, int E) {
  int e = blockIdx.x * 256 + threadIdx.x;
  if (e < E) {
    atomicAdd(&dout[src[e]], 1);
    atomicAdd(&din[dst[e]], 1);
  }
}

__global__ void norms_kernel(const int* __restrict__ dout, const int* __restrict__ din,
                             float* __restrict__ onorm, float* __restrict__ inorm, int n) {
  int v = blockIdx.x * 256 + threadIdx.x;
  if (v < n) {
    int a = dout[v] > 1 ? dout[v] : 1;
    int b = din[v] > 1 ? din[v] : 1;
    onorm[v] = rsqrtf((float)a);
    inorm[v] = rsqrtf((float)b);
  }
}

__global__ void __launch_bounds__(1024) scan_kernel(const int* __restrict__ din,
                                                    int* __restrict__ rp, int n) {
  __shared__ int sums[1024];
  __shared__ int offs[1024];
  int tid = threadIdx.x;
  int chunk = (n + 1023) / 1024;
  int s0 = tid * chunk;
  int s1 = s0 + chunk; if (s1 > n) s1 = n;
  int s = 0;
  for (int i = s0; i < s1; i++) s += din[i];
  sums[tid] = s;
  __syncthreads();
  if (tid == 0) {
    int acc = 0;
    for (int i = 0; i < 1024; i++) { offs[i] = acc; acc += sums[i]; }
    rp[n] = acc;
  }
  __syncthreads();
  int acc = offs[tid];
  for (int i = s0; i < s1; i++) { rp[i] = acc; acc += din[i]; }
}

__global__ void fill_kernel(const int* __restrict__ src, const int* __restrict__ dst,
                            const float* __restrict__ w, const float* __restrict__ onorm,
                            const int* __restrict__ rp, int* __restrict__ cursor,
                            int* __restrict__ col, float* __restrict__ wse, int E) {
  int e = blockIdx.x * 256 + threadIdx.x;
  if (e < E) {
    int d = dst[e];
    int pos = rp[d] + atomicAdd(&cursor[d], 1);
    int s = src[e];
    col[pos] = s;
    wse[pos] = w[e] * onorm[s];
  }
}

// ---------------- dtype prep ----------------

// fp32 -> bf16, 4 elements per thread
__global__ void cvt_x_kernel(const float* __restrict__ x, unsigned short* __restrict__ xb,
                             int n4) {
  int i = blockIdx.x * 256 + threadIdx.x;
  if (i < n4) {
    float4 v = ((const float4*)x)[i];
    uint2 pk;
    pk.x = (unsigned)f2bf(v.x) | ((unsigned)f2bf(v.y) << 16);
    pk.y = (unsigned)f2bf(v.z) | ((unsigned)f2bf(v.w) << 16);
    ((uint2*)xb)[i] = pk;
  }
}

// W [K,N] fp32 -> Wt [N,K] bf16
__global__ void cvt_wt_kernel(const float* __restrict__ W, unsigned short* __restrict__ Wt,
                              int K, int N) {
  int i = blockIdx.x * 256 + threadIdx.x;
  if (i < N * K) {
    int n = i / K, k = i - n * K;
    Wt[i] = f2bf(W[(size_t)k * N + n]);
  }
}

// ---------------- SpMM (bf16 feat, fp32 acc) ----------------
// one block per dst node; F/2 threads, each handles 2 features via one uint load
template <int RELU>
__global__ void spmm_bf16(const unsigned short* __restrict__ feat, int ldf,
                          const int* __restrict__ rp, const int* __restrict__ col,
                          const float* __restrict__ wse,
                          unsigned short* __restrict__ out, int ldo,
                          const float* __restrict__ inorm) {
  int v = blockIdx.x;
  int t = threadIdx.x;
  int beg = rp[v], end = rp[v + 1];
  float a0 = 0.f, a1 = 0.f;
  int e = beg;
  for (; e + 1 < end; e += 2) {
    int s0 = col[e], s1 = col[e + 1];
    float w0 = wse[e], w1 = wse[e + 1];
    unsigned u0 = *(const unsigned*)&feat[(size_t)s0 * ldf + t * 2];
    unsigned u1 = *(const unsigned*)&feat[(size_t)s1 * ldf + t * 2];
    a0 += w0 * bf_lo(u0) + w1 * bf_lo(u1);
    a1 += w0 * bf_hi(u0) + w1 * bf_hi(u1);
  }
  if (e < end) {
    float w0 = wse[e];
    unsigned u0 = *(const unsigned*)&feat[(size_t)col[e] * ldf + t * 2];
    a0 += w0 * bf_lo(u0);
    a1 += w0 * bf_hi(u0);
  }
  if (RELU) {
    float s = inorm[v];
    a0 = fmaxf(a0 * s, 0.f);
    a1 = fmaxf(a1 * s, 0.f);
  }
  *(unsigned*)&out[(size_t)v * ldo + t * 2] =
      (unsigned)f2bf(a0) | ((unsigned)f2bf(a1) << 16);
}

// ---------------- MFMA GEMM: C[M,256-slice] = A[M,K] @ Bt[N,K]^T ----------------
// 128x128 tile, BK=32, 256 threads = 4 waves (2x2), each wave 64x64 (4x4 16x16 tiles).
// A and B staged in LDS in MFMA fragment order -> conflict-free ds_read_b128.
// Fragment (verified m89/m91): A[m=lane&15][k=(lane>>4)*8+j]; C/D col=lane&15,
// row=(lane>>4)*4+reg.
template <int RELU, int OUT32>
__global__ __launch_bounds__(256) void gemm_mfma(
    const unsigned short* __restrict__ A, int lda,
    const unsigned short* __restrict__ Bt,  // [256][K] bf16 (pre-transposed weight)
    void* __restrict__ Cv, int ldc, int M, int K,
    const float* __restrict__ inorm) {
  __shared__ unsigned short As[8 * 512];  // 8 m-tiles x (64 lanes x 8 bf16)
  __shared__ unsigned short Bs[8 * 512];  // 8 n-tiles
  const int tid = threadIdx.x;
  const int lane = tid & 63;
  const int w = tid >> 6;
  const int wm = w >> 1, wn = w & 1;
  const int m0 = blockIdx.x * 128;
  const int n0 = blockIdx.y * 128;
  const int q = lane >> 4;    // k8 group / row-quad
  const int r16 = lane & 15;  // row/col within 16-tile

  f32x4 acc[4][4];
#pragma unroll
  for (int i = 0; i < 4; i++)
#pragma unroll
    for (int j = 0; j < 4; j++) acc[i][j] = (f32x4){0.f, 0.f, 0.f, 0.f};

  const int ta = 2 * w, tb = 2 * w + 1;  // tiles this wave stages

  for (int k0 = 0; k0 < K; k0 += 32) {
    // issue global loads (fragment-order gather: lane = q*16 + r16)
    int gma = m0 + ta * 16 + r16; if (gma >= M) gma = M - 1;
    int gmb = m0 + tb * 16 + r16; if (gmb >= M) gmb = M - 1;
    uint4 va = *(const uint4*)&A[(size_t)gma * lda + k0 + q * 8];
    uint4 vb = *(const uint4*)&A[(size_t)gmb * lda + k0 + q * 8];
    int gna = n0 + ta * 16 + r16;
    int gnb = n0 + tb * 16 + r16;
    uint4 vc = *(const uint4*)&Bt[(size_t)gna * K + k0 + q * 8];
    uint4 vd = *(const uint4*)&Bt[(size_t)gnb * K + k0 + q * 8];
    __syncthreads();  // previous iteration's LDS reads complete
    *(uint4*)&As[ta * 512 + lane * 8] = va;
    *(uint4*)&As[tb * 512 + lane * 8] = vb;
    *(uint4*)&Bs[ta * 512 + lane * 8] = vc;
    *(uint4*)&Bs[tb * 512 + lane * 8] = vd;
    __syncthreads();

    bf16x8 af[4], bfr[4];
#pragma unroll
    for (int i = 0; i < 4; i++)
      af[i] = *(const bf16x8*)&As[(wm * 4 + i) * 512 + lane * 8];
#pragma unroll
    for (int j = 0; j < 4; j++)
      bfr[j] = *(const bf16x8*)&Bs[(wn * 4 + j) * 512 + lane * 8];
#pragma unroll
    for (int i = 0; i < 4; i++)
#pragma unroll
      for (int j = 0; j < 4; j++)
        acc[i][j] = __builtin_amdgcn_mfma_f32_16x16x32_bf16(af[i], bfr[j], acc[i][j], 0, 0, 0);
  }

  // epilogue: row = (lane>>4)*4 + r, col = lane&15
#pragma unroll
  for (int i = 0; i < 4; i++) {
    int rbase = m0 + (wm * 4 + i) * 16 + q * 4;
#pragma unroll
    for (int r = 0; r < 4; r++) {
      int gm = rbase + r;
      if (gm >= M) continue;
      float s = RELU ? inorm[gm] : 1.f;
#pragma unroll
      for (int j = 0; j < 4; j++) {
        float v = acc[i][j][r];
        if (RELU) v = fmaxf(v * s, 0.f);
        int gn = n0 + (wn * 4 + j) * 16 + r16;
        if (OUT32)
          ((float*)Cv)[(size_t)gm * ldc + gn] = v;
        else
          ((unsigned short*)Cv)[(size_t)gm * ldc + gn] = f2bf(v);
      }
    }
  }
}

// ---------------- LayerNorm + relu (bf16 in/out, fp32 stats) ----------------
__global__ void ln_relu_bf16(unsigned short* __restrict__ h, int ld,
                             const float* __restrict__ gamma,
                             const float* __restrict__ beta) {
  int v = blockIdx.x;
  int f = threadIdx.x;  // 256
  float val = bf_lo((unsigned)h[(size_t)v * ld + f]);
  float s = val, qq = val * val;
#pragma unroll
  for (int off = 32; off > 0; off >>= 1) {
    s += __shfl_down(s, off);
    qq += __shfl_down(qq, off);
  }
  __shared__ float ws_[5], wq_[5];
  int wave = f >> 6, lane = f & 63;
  if (lane == 0) { ws_[wave] = s; wq_[wave] = qq; }
  __syncthreads();
  if (f == 0) {
    float S = 0, Q = 0;
    for (int i = 0; i < 4; i++) { S += ws_[i]; Q += wq_[i]; }
    ws_[4] = S; wq_[4] = Q;
  }
  __syncthreads();
  float mean = ws_[4] * (1.f / 256.f);
  float var = wq_[4] * (1.f / 256.f) - mean * mean;
  float y = (val - mean) * rsqrtf(var + EPSF) * gamma[f] + beta[f];
  h[(size_t)v * ld + f] = f2bf(y > 0.f ? y : 0.f);
}

// ---------------- per-graph readout (graph_ids sorted), x3 fp32 ----------------
__global__ void readout_kernel(const float* __restrict__ x3, const int* __restrict__ gid,
                               float* __restrict__ out, int n) {
  int g = blockIdx.x;
  int part = blockIdx.y;  // 8 parts
  int f = threadIdx.x;    // 256
  int lo = 0, hi = n;
  while (lo < hi) { int mid = (lo + hi) >> 1; if (gid[mid] < g) lo = mid + 1; else hi = mid; }
  int s = lo;
  lo = s; hi = n;
  while (lo < hi) { int mid = (lo + hi) >> 1; if (gid[mid] < g + 1) lo = mid + 1; else hi = mid; }
  int e = lo;
  int len = e - s;
  if (len <= 0) return;
  int chunk = (len + 7) / 8;
  int cs = s + part * chunk;
  int ce = cs + chunk; if (ce > e) ce = e;
  if (cs >= ce) return;
  float acc = 0.f;
  for (int v = cs; v < ce; v++) acc += x3[(size_t)v * 256 + f];
  atomicAdd(&out[g * 256 + f], acc);
}

// ---------------- launch ----------------

extern "C" void kernel_launch(void* const* d_in, const int* in_sizes, int n_in,
                              void* d_out, int out_size, void* d_ws, size_t ws_size,
                              hipStream_t stream) {
  const float* x     = (const float*)d_in[0];
  const float* w     = (const float*)d_in[1];
  const float* W1    = (const float*)d_in[2];
  const float* Wfc   = (const float*)d_in[3];
  const float* gamma = (const float*)d_in[4];
  const float* beta  = (const float*)d_in[5];
  const float* W2    = (const float*)d_in[6];
  const float* W3    = (const float*)d_in[7];
  const int*   src   = (const int*)d_in[8];
  const int*   dst   = (const int*)d_in[9];
  const int*   gid   = (const int*)d_in[10];
  float* out = (float*)d_out;

  const int N = NN, E = NE;

  char* p = (char*)d_ws;
  auto alloc = [&](size_t bytes) {
    char* r = p;
    p += (bytes + 255) & ~(size_t)255;
    return r;
  };
  int*   deg_out = (int*)alloc((size_t)N * 4);
  int*   deg_in  = (int*)alloc((size_t)N * 4);
  float* onorm   = (float*)alloc((size_t)N * 4);
  float* inorm   = (float*)alloc((size_t)N * 4);
  int*   row_ptr = (int*)alloc((size_t)(N + 1) * 4);
  int*   cursor  = (int*)alloc((size_t)N * 4);
  int*   col     = (int*)alloc((size_t)E * 4);
  float* wse     = (float*)alloc((size_t)E * 4);
  unsigned short* xb    = (unsigned short*)alloc((size_t)N * 128 * 2);
  unsigned short* aggX  = (unsigned short*)alloc((size_t)N * 128 * 2);
  unsigned short* x1f1  = (unsigned short*)alloc((size_t)N * 512 * 2);  // also x3 (fp32) later
  unsigned short* y2    = (unsigned short*)alloc((size_t)N * 256 * 2);
  unsigned short* x2    = (unsigned short*)alloc((size_t)N * 256 * 2);
  unsigned short* aggx2 = (unsigned short*)alloc((size_t)N * 256 * 2);
  unsigned short* W1t   = (unsigned short*)alloc((size_t)256 * 128 * 2);
  unsigned short* Wfct  = (unsigned short*)alloc((size_t)256 * 128 * 2);
  unsigned short* W2t   = (unsigned short*)alloc((size_t)256 * 512 * 2);
  unsigned short* W3t   = (unsigned short*)alloc((size_t)256 * 256 * 2);
  float* x3 = (float*)x1f1;  // x1f1 dead once y2 is computed; reuse (same 51.2 MB)

  hipMemsetAsync(deg_out, 0, (size_t)N * 4, stream);
  hipMemsetAsync(deg_in, 0, (size_t)N * 4, stream);
  hipMemsetAsync(cursor, 0, (size_t)N * 4, stream);
  hipMemsetAsync(out, 0, (size_t)NG * 256 * 4, stream);

  deg_kernel<<<(E + 255) / 256, 256, 0, stream>>>(src, dst, deg_out, deg_in, E);
  norms_kernel<<<(N + 255) / 256, 256, 0, stream>>>(deg_out, deg_in, onorm, inorm, N);
  scan_kernel<<<1, 1024, 0, stream>>>(deg_in, row_ptr, N);
  fill_kernel<<<(E + 255) / 256, 256, 0, stream>>>(src, dst, w, onorm, row_ptr, cursor,
                                                   col, wse, E);

  cvt_x_kernel<<<(N * 128 / 4 + 255) / 256, 256, 0, stream>>>(x, xb, N * 128 / 4);
  cvt_wt_kernel<<<(256 * 128 + 255) / 256, 256, 0, stream>>>(W1, W1t, 128, 256);
  cvt_wt_kernel<<<(256 * 128 + 255) / 256, 256, 0, stream>>>(Wfc, Wfct, 128, 256);
  cvt_wt_kernel<<<(256 * 512 + 255) / 256, 256, 0, stream>>>(W2, W2t, 512, 256);
  cvt_wt_kernel<<<(256 * 256 + 255) / 256, 256, 0, stream>>>(W3, W3t, 256, 256);

  dim3 ggrid((N + 127) / 128, 2);  // 391 x 2

  // aggX = agg(xb)
  spmm_bf16<0><<<N, 64, 0, stream>>>(xb, 128, row_ptr, col, wse, aggX, 128, inorm);
  // x1 = relu(inorm * (aggX @ W1)) -> x1f1[:, 0:256] bf16
  gemm_mfma<1, 0><<<ggrid, 256, 0, stream>>>(aggX, 128, W1t, x1f1, 512, N, 128, inorm);
  // f1pre = xb @ Wfc -> x1f1[:, 256:512] bf16
  gemm_mfma<0, 0><<<ggrid, 256, 0, stream>>>(xb, 128, Wfct, x1f1 + 256, 512, N, 128, inorm);
  // f1 = relu(LN(f1pre)) in place
  ln_relu_bf16<<<N, 256, 0, stream>>>(x1f1 + 256, 512, gamma, beta);
  // y2 = x1f1 @ W2
  gemm_mfma<0, 0><<<ggrid, 256, 0, stream>>>(x1f1, 512, W2t, y2, 256, N, 512, inorm);
  // x2 = relu(inorm * agg(y2))
  spmm_bf16<1><<<N, 128, 0, stream>>>(y2, 256, row_ptr, col, wse, x2, 256, inorm);
  // aggx2 = agg(x2)
  spmm_bf16<0><<<N, 128, 0, stream>>>(x2, 256, row_ptr, col, wse, aggx2, 256, inorm);
  // x3 = relu(inorm * (aggx2 @ W3)) fp32 (into x1f1's storage)
  gemm_mfma<1, 1><<<ggrid, 256, 0, stream>>>(aggx2, 256, W3t, x3, 256, N, 256, inorm);
  // readout
  readout_kernel<<<dim3(NG, 8), 256, 0, stream>>>(x3, gid, out, N);
}

// Round 3
// 551.052 us; speedup vs baseline: 1.9494x; 1.1785x over previous
//
#include <hip/hip_runtime.h>

#define NN 50000
#define NE 800000
#define NG 64
#define EPSF 1e-5f

typedef __bf16 bf16x8 __attribute__((ext_vector_type(8)));
typedef float f32x4 __attribute__((ext_vector_type(4)));

#define AS1 __attribute__((address_space(1)))
#define AS3 __attribute__((address_space(3)))

__device__ __forceinline__ void gl_lds16(const unsigned short* g, unsigned short* l) {
#if __has_builtin(__builtin_amdgcn_global_load_lds)
  __builtin_amdgcn_global_load_lds((const AS1 void*)g, (AS3 void*)l, 16, 0, 0);
#else
  *(uint4*)l = *(const uint4*)g;   // fallback (sync)
#endif
}

__device__ __forceinline__ unsigned short f2bf(float f) {
  unsigned u = __builtin_bit_cast(unsigned, f);
  u += 0x7fff + ((u >> 16) & 1);   // RNE (finite values only here)
  return (unsigned short)(u >> 16);
}
__device__ __forceinline__ float bf_lo(unsigned u) {
  return __builtin_bit_cast(float, u << 16);
}
__device__ __forceinline__ float bf_hi(unsigned u) {
  return __builtin_bit_cast(float, u & 0xffff0000u);
}

// ---------------- degree / norms ----------------

__global__ void deg_kernel(const int* __restrict__ src, const int* __restrict__ dst,
                           int* __restrict__ dout, int* __restrict__ din, int E) {
  int e = blockIdx.x * 256 + threadIdx.x;
  if (e < E) {
    atomicAdd(&dout[src[e]], 1);
    atomicAdd(&din[dst[e]], 1);
  }
}

__global__ void norms_kernel(const int* __restrict__ dout, const int* __restrict__ din,
                             float* __restrict__ onorm, float* __restrict__ inorm, int n) {
  int v = blockIdx.x * 256 + threadIdx.x;
  if (v < n) {
    int a = dout[v] > 1 ? dout[v] : 1;
    int b = din[v] > 1 ? din[v] : 1;
    onorm[v] = rsqrtf((float)a);
    inorm[v] = rsqrtf((float)b);
  }
}

// ---------------- parallel exclusive scan (3 phases) ----------------

__global__ void scan1_kernel(const int* __restrict__ din, int* __restrict__ bsum, int n) {
  int i = blockIdx.x * 256 + threadIdx.x;
  int v = (i < n) ? din[i] : 0;
#pragma unroll
  for (int off = 32; off > 0; off >>= 1) v += __shfl_down(v, off);
  __shared__ int ws[4];
  int wave = threadIdx.x >> 6, lane = threadIdx.x & 63;
  if (lane == 0) ws[wave] = v;
  __syncthreads();
  if (threadIdx.x == 0) bsum[blockIdx.x] = ws[0] + ws[1] + ws[2] + ws[3];
}

// one block, 256 threads: exclusive-scan up to 256 block sums; writes rp[n]=total
__global__ void scan2_kernel(const int* __restrict__ bsum, int* __restrict__ boff,
                             int nb, int* __restrict__ rp, int n) {
  int t = threadIdx.x;
  int v = (t < nb) ? bsum[t] : 0;
  __shared__ int tmp[256];
  tmp[t] = v;
  __syncthreads();
  for (int off = 1; off < 256; off <<= 1) {
    int x = (t >= off) ? tmp[t - off] : 0;
    __syncthreads();
    tmp[t] += x;
    __syncthreads();
  }
  if (t < nb) boff[t] = tmp[t] - v;
  if (t == 255) rp[n] = tmp[255];
}

__global__ void scan3_kernel(const int* __restrict__ din, const int* __restrict__ boff,
                             int* __restrict__ rp, int n) {
  int t = threadIdx.x;
  int i = blockIdx.x * 256 + t;
  int v = (i < n) ? din[i] : 0;
  __shared__ int tmp[256];
  tmp[t] = v;
  __syncthreads();
  for (int off = 1; off < 256; off <<= 1) {
    int x = (t >= off) ? tmp[t - off] : 0;
    __syncthreads();
    tmp[t] += x;
    __syncthreads();
  }
  if (i < n) rp[i] = tmp[t] - v + boff[blockIdx.x];
}

__global__ void fill_kernel(const int* __restrict__ src, const int* __restrict__ dst,
                            const float* __restrict__ w, const float* __restrict__ onorm,
                            const int* __restrict__ rp, int* __restrict__ cursor,
                            int* __restrict__ col, float* __restrict__ wse, int E) {
  int e = blockIdx.x * 256 + threadIdx.x;
  if (e < E) {
    int d = dst[e];
    int pos = rp[d] + atomicAdd(&cursor[d], 1);
    int s = src[e];
    col[pos] = s;
    wse[pos] = w[e] * onorm[s];
  }
}

// ---------------- dtype prep ----------------

__global__ void cvt_x_kernel(const float* __restrict__ x, unsigned short* __restrict__ xb,
                             int n4) {
  int i = blockIdx.x * 256 + threadIdx.x;
  if (i < n4) {
    float4 v = ((const float4*)x)[i];
    uint2 pk;
    pk.x = (unsigned)f2bf(v.x) | ((unsigned)f2bf(v.y) << 16);
    pk.y = (unsigned)f2bf(v.z) | ((unsigned)f2bf(v.w) << 16);
    ((uint2*)xb)[i] = pk;
  }
}

// W [K,N] fp32 -> Wt [N,K] bf16
__global__ void cvt_wt_kernel(const float* __restrict__ W, unsigned short* __restrict__ Wt,
                              int K, int N) {
  int i = blockIdx.x * 256 + threadIdx.x;
  if (i < N * K) {
    int n = i / K, k = i - n * K;
    Wt[i] = f2bf(W[(size_t)k * N + n]);
  }
}

// ---------------- SpMM (bf16 feat, fp32 acc) ----------------
// one 64-thread block per dst node; NU uints (=2*NU feats) per thread.
// col/wse indices are wave-uniform -> scalar loads.
template <int RELU, int NU>
__global__ __launch_bounds__(64) void spmm_bf16(
    const unsigned short* __restrict__ feat, int ldf,
    const int* __restrict__ rp, const int* __restrict__ col,
    const float* __restrict__ wse,
    unsigned short* __restrict__ out, int ldo,
    const float* __restrict__ inorm) {
  int v = blockIdx.x;
  int t = threadIdx.x;  // 64
  int beg = rp[v], end = rp[v + 1];
  float acc[2 * NU];
#pragma unroll
  for (int i = 0; i < 2 * NU; i++) acc[i] = 0.f;
  const unsigned short* base = feat + t * (2 * NU);
  int e = beg;
  for (; e + 4 <= end; e += 4) {
    int s[4]; float ww[4];
#pragma unroll
    for (int k = 0; k < 4; k++) { s[k] = col[e + k]; ww[k] = wse[e + k]; }
    unsigned u[4][NU];
#pragma unroll
    for (int k = 0; k < 4; k++) {
      const unsigned* pr = (const unsigned*)&base[(size_t)s[k] * ldf];
      if (NU == 2) { uint2 q = *(const uint2*)pr; u[k][0] = q.x; u[k][NU - 1] = q.y; }
      else u[k][0] = pr[0];
    }
#pragma unroll
    for (int k = 0; k < 4; k++)
#pragma unroll
      for (int j = 0; j < NU; j++) {
        acc[2 * j]     += ww[k] * bf_lo(u[k][j]);
        acc[2 * j + 1] += ww[k] * bf_hi(u[k][j]);
      }
  }
  for (; e < end; e++) {
    float w0 = wse[e];
    const unsigned* pr = (const unsigned*)&base[(size_t)col[e] * ldf];
    unsigned u[NU];
    if (NU == 2) { uint2 q = *(const uint2*)pr; u[0] = q.x; u[NU - 1] = q.y; }
    else u[0] = pr[0];
#pragma unroll
    for (int j = 0; j < NU; j++) {
      acc[2 * j]     += w0 * bf_lo(u[j]);
      acc[2 * j + 1] += w0 * bf_hi(u[j]);
    }
  }
  float sc = RELU ? inorm[v] : 1.f;
  unsigned o[NU];
#pragma unroll
  for (int j = 0; j < NU; j++) {
    float a = acc[2 * j], b = acc[2 * j + 1];
    if (RELU) { a = fmaxf(a * sc, 0.f); b = fmaxf(b * sc, 0.f); }
    o[j] = (unsigned)f2bf(a) | ((unsigned)f2bf(b) << 16);
  }
  unsigned* po = (unsigned*)&out[(size_t)v * ldo + t * (2 * NU)];
  if (NU == 2) *(uint2*)po = make_uint2(o[0], o[NU - 1]);
  else po[0] = o[0];
}

// ---------------- MFMA GEMM: C[M,128-slice] = A[M,K] @ Bt[N,K]^T ----------------
// 128x128 tile, BK=32, 4 waves (2x2), each wave 4x4 16x16x32 tiles.
// LDS staged via global_load_lds (wave-uniform base + lane*16B, fragment order).
template <int RELU, int OUT32>
__global__ __launch_bounds__(256) void gemm_mfma(
    const unsigned short* __restrict__ A, int lda,
    const unsigned short* __restrict__ Bt,  // [256][K] bf16
    void* __restrict__ Cv, int ldc, int M, int K,
    const float* __restrict__ inorm) {
  __shared__ unsigned short As[8 * 512];
  __shared__ unsigned short Bs[8 * 512];
  const int tid = threadIdx.x;
  const int lane = tid & 63;
  const int w = tid >> 6;
  const int wm = w >> 1, wn = w & 1;
  const int m0 = blockIdx.x * 128;
  const int n0 = blockIdx.y * 128;
  const int q = lane >> 4;
  const int r16 = lane & 15;

  f32x4 acc[4][4];
#pragma unroll
  for (int i = 0; i < 4; i++)
#pragma unroll
    for (int j = 0; j < 4; j++) acc[i][j] = (f32x4){0.f, 0.f, 0.f, 0.f};

  const int ta = 2 * w, tb = 2 * w + 1;
  int gma = m0 + ta * 16 + r16; if (gma >= M) gma = M - 1;
  int gmb = m0 + tb * 16 + r16; if (gmb >= M) gmb = M - 1;
  const int gna = n0 + ta * 16 + r16;
  const int gnb = n0 + tb * 16 + r16;
  const unsigned short* pa = A + (size_t)gma * lda + q * 8;
  const unsigned short* pb = A + (size_t)gmb * lda + q * 8;
  const unsigned short* pc = Bt + (size_t)gna * K + q * 8;
  const unsigned short* pd = Bt + (size_t)gnb * K + q * 8;

  for (int k0 = 0; k0 < K; k0 += 32) {
    __syncthreads();  // prior iteration's LDS reads complete
    gl_lds16(pa + k0, &As[ta * 512 + lane * 8]);
    gl_lds16(pb + k0, &As[tb * 512 + lane * 8]);
    gl_lds16(pc + k0, &Bs[ta * 512 + lane * 8]);
    gl_lds16(pd + k0, &Bs[tb * 512 + lane * 8]);
    __syncthreads();  // vmcnt drained -> tiles in LDS

    bf16x8 af[4], bfr[4];
#pragma unroll
    for (int i = 0; i < 4; i++)
      af[i] = *(const bf16x8*)&As[(wm * 4 + i) * 512 + lane * 8];
#pragma unroll
    for (int j = 0; j < 4; j++)
      bfr[j] = *(const bf16x8*)&Bs[(wn * 4 + j) * 512 + lane * 8];
#pragma unroll
    for (int i = 0; i < 4; i++)
#pragma unroll
      for (int j = 0; j < 4; j++)
        acc[i][j] = __builtin_amdgcn_mfma_f32_16x16x32_bf16(af[i], bfr[j], acc[i][j], 0, 0, 0);
  }

  // epilogue: row = q*4 + r, col = r16
#pragma unroll
  for (int i = 0; i < 4; i++) {
    int rbase = m0 + (wm * 4 + i) * 16 + q * 4;
#pragma unroll
    for (int r = 0; r < 4; r++) {
      int gm = rbase + r;
      if (gm >= M) continue;
      float s = RELU ? inorm[gm] : 1.f;
#pragma unroll
      for (int j = 0; j < 4; j++) {
        float v = acc[i][j][r];
        if (RELU) v = fmaxf(v * s, 0.f);
        int gn = n0 + (wn * 4 + j) * 16 + r16;
        if (OUT32)
          ((float*)Cv)[(size_t)gm * ldc + gn] = v;
        else
          ((unsigned short*)Cv)[(size_t)gm * ldc + gn] = f2bf(v);
      }
    }
  }
}

// ---------------- LayerNorm + relu (bf16 in/out, fp32 stats) ----------------
__global__ void ln_relu_bf16(unsigned short* __restrict__ h, int ld,
                             const float* __restrict__ gamma,
                             const float* __restrict__ beta) {
  int v = blockIdx.x;
  int f = threadIdx.x;  // 256
  float val = bf_lo((unsigned)h[(size_t)v * ld + f]);
  float s = val, qq = val * val;
#pragma unroll
  for (int off = 32; off > 0; off >>= 1) {
    s += __shfl_down(s, off);
    qq += __shfl_down(qq, off);
  }
  __shared__ float ws_[5], wq_[5];
  int wave = f >> 6, lane = f & 63;
  if (lane == 0) { ws_[wave] = s; wq_[wave] = qq; }
  __syncthreads();
  if (f == 0) {
    float S = 0, Q = 0;
    for (int i = 0; i < 4; i++) { S += ws_[i]; Q += wq_[i]; }
    ws_[4] = S; wq_[4] = Q;
  }
  __syncthreads();
  float mean = ws_[4] * (1.f / 256.f);
  float var = wq_[4] * (1.f / 256.f) - mean * mean;
  float y = (val - mean) * rsqrtf(var + EPSF) * gamma[f] + beta[f];
  h[(size_t)v * ld + f] = f2bf(y > 0.f ? y : 0.f);
}

// ---------------- per-graph readout (graph_ids sorted), x3 fp32 ----------------
__global__ void readout_kernel(const float* __restrict__ x3, const int* __restrict__ gid,
                               float* __restrict__ out, int n) {
  int g = blockIdx.x;
  int part = blockIdx.y;  // 8 parts
  int f = threadIdx.x;    // 256
  int lo = 0, hi = n;
  while (lo < hi) { int mid = (lo + hi) >> 1; if (gid[mid] < g) lo = mid + 1; else hi = mid; }
  int s = lo;
  lo = s; hi = n;
  while (lo < hi) { int mid = (lo + hi) >> 1; if (gid[mid] < g + 1) lo = mid + 1; else hi = mid; }
  int e = lo;
  int len = e - s;
  if (len <= 0) return;
  int chunk = (len + 7) / 8;
  int cs = s + part * chunk;
  int ce = cs + chunk; if (ce > e) ce = e;
  if (cs >= ce) return;
  float acc = 0.f;
  for (int v = cs; v < ce; v++) acc += x3[(size_t)v * 256 + f];
  atomicAdd(&out[g * 256 + f], acc);
}

// ---------------- launch ----------------

extern "C" void kernel_launch(void* const* d_in, const int* in_sizes, int n_in,
                              void* d_out, int out_size, void* d_ws, size_t ws_size,
                              hipStream_t stream) {
  const float* x     = (const float*)d_in[0];
  const float* w     = (const float*)d_in[1];
  const float* W1    = (const float*)d_in[2];
  const float* Wfc   = (const float*)d_in[3];
  const float* gamma = (const float*)d_in[4];
  const float* beta  = (const float*)d_in[5];
  const float* W2    = (const float*)d_in[6];
  const float* W3    = (const float*)d_in[7];
  const int*   src   = (const int*)d_in[8];
  const int*   dst   = (const int*)d_in[9];
  const int*   gid   = (const int*)d_in[10];
  float* out = (float*)d_out;

  const int N = NN, E = NE;

  char* p = (char*)d_ws;
  auto alloc = [&](size_t bytes) {
    char* r = p;
    p += (bytes + 255) & ~(size_t)255;
    return r;
  };
  int*   deg_out = (int*)alloc((size_t)N * 4);
  int*   deg_in  = (int*)alloc((size_t)N * 4);
  float* onorm   = (float*)alloc((size_t)N * 4);
  float* inorm   = (float*)alloc((size_t)N * 4);
  int*   row_ptr = (int*)alloc((size_t)(N + 1) * 4);
  int*   cursor  = (int*)alloc((size_t)N * 4);
  int*   bsum    = (int*)alloc(256 * 4);
  int*   boff    = (int*)alloc(256 * 4);
  int*   col     = (int*)alloc((size_t)E * 4);
  float* wse     = (float*)alloc((size_t)E * 4);
  unsigned short* xb    = (unsigned short*)alloc((size_t)N * 128 * 2);
  unsigned short* aggX  = (unsigned short*)alloc((size_t)N * 128 * 2);
  unsigned short* x1f1  = (unsigned short*)alloc((size_t)N * 512 * 2);
  unsigned short* y2    = (unsigned short*)alloc((size_t)N * 256 * 2);
  unsigned short* x2    = (unsigned short*)alloc((size_t)N * 256 * 2);
  unsigned short* aggx2 = (unsigned short*)alloc((size_t)N * 256 * 2);
  unsigned short* W1t   = (unsigned short*)alloc((size_t)256 * 128 * 2);
  unsigned short* Wfct  = (unsigned short*)alloc((size_t)256 * 128 * 2);
  unsigned short* W2t   = (unsigned short*)alloc((size_t)256 * 512 * 2);
  unsigned short* W3t   = (unsigned short*)alloc((size_t)256 * 256 * 2);
  float* x3 = (float*)x1f1;  // x1f1 dead after y2 GEMM; reuse storage (same 51.2 MB)

  hipMemsetAsync(deg_out, 0, (size_t)N * 4, stream);
  hipMemsetAsync(deg_in, 0, (size_t)N * 4, stream);
  hipMemsetAsync(cursor, 0, (size_t)N * 4, stream);
  hipMemsetAsync(out, 0, (size_t)NG * 256 * 4, stream);

  const int nbS = (N + 255) / 256;  // 196

  deg_kernel<<<(E + 255) / 256, 256, 0, stream>>>(src, dst, deg_out, deg_in, E);
  norms_kernel<<<nbS, 256, 0, stream>>>(deg_out, deg_in, onorm, inorm, N);
  scan1_kernel<<<nbS, 256, 0, stream>>>(deg_in, bsum, N);
  scan2_kernel<<<1, 256, 0, stream>>>(bsum, boff, nbS, row_ptr, N);
  scan3_kernel<<<nbS, 256, 0, stream>>>(deg_in, boff, row_ptr, N);
  fill_kernel<<<(E + 255) / 256, 256, 0, stream>>>(src, dst, w, onorm, row_ptr, cursor,
                                                   col, wse, E);

  cvt_x_kernel<<<(N * 128 / 4 + 255) / 256, 256, 0, stream>>>(x, xb, N * 128 / 4);
  cvt_wt_kernel<<<(256 * 128 + 255) / 256, 256, 0, stream>>>(W1, W1t, 128, 256);
  cvt_wt_kernel<<<(256 * 128 + 255) / 256, 256, 0, stream>>>(Wfc, Wfct, 128, 256);
  cvt_wt_kernel<<<(256 * 512 + 255) / 256, 256, 0, stream>>>(W2, W2t, 512, 256);
  cvt_wt_kernel<<<(256 * 256 + 255) / 256, 256, 0, stream>>>(W3, W3t, 256, 256);

  dim3 ggrid((N + 127) / 128, 2);  // 391 x 2

  // aggX = agg(xb)
  spmm_bf16<0, 1><<<N, 64, 0, stream>>>(xb, 128, row_ptr, col, wse, aggX, 128, inorm);
  // x1 = relu(inorm * (aggX @ W1)) -> x1f1[:, 0:256]
  gemm_mfma<1, 0><<<ggrid, 256, 0, stream>>>(aggX, 128, W1t, x1f1, 512, N, 128, inorm);
  // f1pre = xb @ Wfc -> x1f1[:, 256:512]
  gemm_mfma<0, 0><<<ggrid, 256, 0, stream>>>(xb, 128, Wfct, x1f1 + 256, 512, N, 128, inorm);
  // f1 = relu(LN(f1pre)) in place
  ln_relu_bf16<<<N, 256, 0, stream>>>(x1f1 + 256, 512, gamma, beta);
  // y2 = x1f1 @ W2
  gemm_mfma<0, 0><<<ggrid, 256, 0, stream>>>(x1f1, 512, W2t, y2, 256, N, 512, inorm);
  // x2 = relu(inorm * agg(y2))
  spmm_bf16<1, 2><<<N, 64, 0, stream>>>(y2, 256, row_ptr, col, wse, x2, 256, inorm);
  // aggx2 = agg(x2)
  spmm_bf16<0, 2><<<N, 64, 0, stream>>>(x2, 256, row_ptr, col, wse, aggx2, 256, inorm);
  // x3 = relu(inorm * (aggx2 @ W3)) fp32
  gemm_mfma<1, 1><<<ggrid, 256, 0, stream>>>(aggx2, 256, W3t, x3, 256, N, 256, inorm);
  // readout
  readout_kernel<<<dim3(NG, 8), 256, 0, stream>>>(x3, gid, out, N);
}

// Round 5
// 523.311 us; speedup vs baseline: 2.0527x; 1.0530x over previous
//
#include <hip/hip_runtime.h>

#define NN 50000
#define NE 800000
#define NG 64
#define EPSF 1e-5f

typedef __bf16 bf16x8 __attribute__((ext_vector_type(8)));
typedef float f32x4 __attribute__((ext_vector_type(4)));

#define AS1 __attribute__((address_space(1)))
#define AS3 __attribute__((address_space(3)))

__device__ __forceinline__ void gl_lds16(const unsigned short* g, unsigned short* l) {
#if __has_builtin(__builtin_amdgcn_global_load_lds)
  __builtin_amdgcn_global_load_lds((const AS1 void*)g, (AS3 void*)l, 16, 0, 0);
#else
  *(uint4*)l = *(const uint4*)g;
#endif
}

__device__ __forceinline__ unsigned short f2bf(float f) {
  unsigned u = __builtin_bit_cast(unsigned, f);
  u += 0x7fff + ((u >> 16) & 1);  // RNE
  return (unsigned short)(u >> 16);
}
__device__ __forceinline__ float bf_lo(unsigned u) {
  return __builtin_bit_cast(float, u << 16);
}
__device__ __forceinline__ float bf_hi(unsigned u) {
  return __builtin_bit_cast(float, u & 0xffff0000u);
}

// ---------------- degree + rank (one atomic pass) ----------------
// rank[e] = ordinal of edge e within its dst row == old value of din counter.
__global__ void deg_rank_kernel(const int* __restrict__ src, const int* __restrict__ dst,
                                int* __restrict__ dout, int* __restrict__ din,
                                int* __restrict__ rank, int E) {
  int e = blockIdx.x * 256 + threadIdx.x;
  if (e < E) {
    atomicAdd(&dout[src[e]], 1);
    rank[e] = atomicAdd(&din[dst[e]], 1);
  }
}

__global__ void norms_kernel(const int* __restrict__ dout, const int* __restrict__ din,
                             float* __restrict__ onorm, float* __restrict__ inorm, int n) {
  int v = blockIdx.x * 256 + threadIdx.x;
  if (v < n) {
    int a = dout[v] > 1 ? dout[v] : 1;
    int b = din[v] > 1 ? din[v] : 1;
    onorm[v] = rsqrtf((float)a);
    inorm[v] = rsqrtf((float)b);
  }
}

// ---------------- parallel exclusive scan (3 phases) ----------------

__global__ void scan1_kernel(const int* __restrict__ din, int* __restrict__ bsum, int n) {
  int i = blockIdx.x * 256 + threadIdx.x;
  int v = (i < n) ? din[i] : 0;
#pragma unroll
  for (int off = 32; off > 0; off >>= 1) v += __shfl_down(v, off);
  __shared__ int ws[4];
  int wave = threadIdx.x >> 6, lane = threadIdx.x & 63;
  if (lane == 0) ws[wave] = v;
  __syncthreads();
  if (threadIdx.x == 0) bsum[blockIdx.x] = ws[0] + ws[1] + ws[2] + ws[3];
}

__global__ void scan2_kernel(const int* __restrict__ bsum, int* __restrict__ boff,
                             int nb, int* __restrict__ rp, int n) {
  int t = threadIdx.x;
  int v = (t < nb) ? bsum[t] : 0;
  __shared__ int tmp[256];
  tmp[t] = v;
  __syncthreads();
  for (int off = 1; off < 256; off <<= 1) {
    int x = (t >= off) ? tmp[t - off] : 0;
    __syncthreads();
    tmp[t] += x;
    __syncthreads();
  }
  if (t < nb) boff[t] = tmp[t] - v;
  if (t == 255) rp[n] = tmp[255];
}

__global__ void scan3_kernel(const int* __restrict__ din, const int* __restrict__ boff,
                             int* __restrict__ rp, int n) {
  int t = threadIdx.x;
  int i = blockIdx.x * 256 + t;
  int v = (i < n) ? din[i] : 0;
  __shared__ int tmp[256];
  tmp[t] = v;
  __syncthreads();
  for (int off = 1; off < 256; off <<= 1) {
    int x = (t >= off) ? tmp[t - off] : 0;
    __syncthreads();
    tmp[t] += x;
    __syncthreads();
  }
  if (i < n) rp[i] = tmp[t] - v + boff[blockIdx.x];
}

// ---------------- CSR fill, atomic-free; wse = w * onorm[src] * inorm[dst] ----------------
__global__ void fill_kernel(const int* __restrict__ src, const int* __restrict__ dst,
                            const float* __restrict__ w, const float* __restrict__ onorm,
                            const float* __restrict__ inorm,
                            const int* __restrict__ rp, const int* __restrict__ rank,
                            int* __restrict__ col, float* __restrict__ wse, int E) {
  int e = blockIdx.x * 256 + threadIdx.x;
  if (e < E) {
    int d = dst[e], s = src[e];
    int pos = rp[d] + rank[e];
    col[pos] = s;
    wse[pos] = w[e] * onorm[s] * inorm[d];
  }
}

// ---------------- dtype prep ----------------

__global__ void cvt_x_kernel(const float* __restrict__ x, unsigned short* __restrict__ xb,
                             int n4) {
  int i = blockIdx.x * 256 + threadIdx.x;
  if (i < n4) {
    float4 v = ((const float4*)x)[i];
    uint2 pk;
    pk.x = (unsigned)f2bf(v.x) | ((unsigned)f2bf(v.y) << 16);
    pk.y = (unsigned)f2bf(v.z) | ((unsigned)f2bf(v.w) << 16);
    ((uint2*)xb)[i] = pk;
  }
}

// all four weights [K,256] fp32 -> [256,K] bf16, one dispatch
__global__ void cvt_wt_all(const float* __restrict__ W1, const float* __restrict__ Wfc,
                           const float* __restrict__ W2, const float* __restrict__ W3,
                           unsigned short* __restrict__ W1t, unsigned short* __restrict__ Wfct,
                           unsigned short* __restrict__ W2t, unsigned short* __restrict__ W3t) {
  int i = blockIdx.x * 256 + threadIdx.x;  // 0 .. 262143
  const float* W; unsigned short* Wt; int K, local;
  if (i < 32768)        { W = W1;  Wt = W1t;  K = 128; local = i; }
  else if (i < 65536)   { W = Wfc; Wt = Wfct; K = 128; local = i - 32768; }
  else if (i < 196608)  { W = W2;  Wt = W2t;  K = 512; local = i - 65536; }
  else                  { W = W3;  Wt = W3t;  K = 256; local = i - 196608; }
  int n = local / K, k = local - n * K;
  Wt[local] = f2bf(W[(size_t)k * 256 + n]);
}

// ---------------- SpMM (bf16 feat, fp32 acc); norms pre-folded into wse ----------------
template <int RELU, int NU>
__global__ __launch_bounds__(64) void spmm_bf16(
    const unsigned short* __restrict__ feat, int ldf,
    const int* __restrict__ rp, const int* __restrict__ col,
    const float* __restrict__ wse,
    unsigned short* __restrict__ out, int ldo) {
  int v = blockIdx.x;
  int t = threadIdx.x;  // 64
  int beg = rp[v], end = rp[v + 1];
  float acc[2 * NU];
#pragma unroll
  for (int i = 0; i < 2 * NU; i++) acc[i] = 0.f;
  const unsigned short* base = feat + t * (2 * NU);
  int e = beg;
  for (; e + 4 <= end; e += 4) {
    int s[4]; float ww[4];
#pragma unroll
    for (int k = 0; k < 4; k++) { s[k] = col[e + k]; ww[k] = wse[e + k]; }
    unsigned u[4][NU];
#pragma unroll
    for (int k = 0; k < 4; k++) {
      const unsigned* pr = (const unsigned*)&base[(size_t)s[k] * ldf];
      if (NU == 2) { uint2 q = *(const uint2*)pr; u[k][0] = q.x; u[k][NU - 1] = q.y; }
      else u[k][0] = pr[0];
    }
#pragma unroll
    for (int k = 0; k < 4; k++)
#pragma unroll
      for (int j = 0; j < NU; j++) {
        acc[2 * j]     += ww[k] * bf_lo(u[k][j]);
        acc[2 * j + 1] += ww[k] * bf_hi(u[k][j]);
      }
  }
  for (; e < end; e++) {
    float w0 = wse[e];
    const unsigned* pr = (const unsigned*)&base[(size_t)col[e] * ldf];
    unsigned u[NU];
    if (NU == 2) { uint2 q = *(const uint2*)pr; u[0] = q.x; u[NU - 1] = q.y; }
    else u[0] = pr[0];
#pragma unroll
    for (int j = 0; j < NU; j++) {
      acc[2 * j]     += w0 * bf_lo(u[j]);
      acc[2 * j + 1] += w0 * bf_hi(u[j]);
    }
  }
  unsigned o[NU];
#pragma unroll
  for (int j = 0; j < NU; j++) {
    float a = acc[2 * j], b = acc[2 * j + 1];
    if (RELU) { a = fmaxf(a, 0.f); b = fmaxf(b, 0.f); }
    o[j] = (unsigned)f2bf(a) | ((unsigned)f2bf(b) << 16);
  }
  unsigned* po = (unsigned*)&out[(size_t)v * ldo + t * (2 * NU)];
  if (NU == 2) *(uint2*)po = make_uint2(o[0], o[NU - 1]);
  else po[0] = o[0];
}

// ---------------- MFMA GEMM body: C[:,128-slice] = A[M,K] @ Bt[N,K]^T ----------------
// 128x128 tile, BK=32, 4 waves (2x2), each wave 4x4 16x16x32 tiles.
__device__ __forceinline__ void gemm_body(
    const unsigned short* __restrict__ A, int lda,
    const unsigned short* __restrict__ Bt, int K,
    void* __restrict__ Cv, int ldc, int col_off, int M,
    int relu, int out32,
    unsigned short* As, unsigned short* Bs) {
  const int tid = threadIdx.x;
  const int lane = tid & 63;
  const int w = tid >> 6;
  const int wm = w >> 1, wn = w & 1;
  const int m0 = blockIdx.x * 128;
  const int n0 = blockIdx.y * 128;
  const int q = lane >> 4;
  const int r16 = lane & 15;

  f32x4 acc[4][4];
#pragma unroll
  for (int i = 0; i < 4; i++)
#pragma unroll
    for (int j = 0; j < 4; j++) acc[i][j] = (f32x4){0.f, 0.f, 0.f, 0.f};

  const int ta = 2 * w, tb = 2 * w + 1;
  int gma = m0 + ta * 16 + r16; if (gma >= M) gma = M - 1;
  int gmb = m0 + tb * 16 + r16; if (gmb >= M) gmb = M - 1;
  const int gna = n0 + ta * 16 + r16;
  const int gnb = n0 + tb * 16 + r16;
  const unsigned short* pa = A + (size_t)gma * lda + q * 8;
  const unsigned short* pb = A + (size_t)gmb * lda + q * 8;
  const unsigned short* pc = Bt + (size_t)gna * K + q * 8;
  const unsigned short* pd = Bt + (size_t)gnb * K + q * 8;

  for (int k0 = 0; k0 < K; k0 += 32) {
    __syncthreads();
    gl_lds16(pa + k0, &As[ta * 512 + lane * 8]);
    gl_lds16(pb + k0, &As[tb * 512 + lane * 8]);
    gl_lds16(pc + k0, &Bs[ta * 512 + lane * 8]);
    gl_lds16(pd + k0, &Bs[tb * 512 + lane * 8]);
    __syncthreads();

    bf16x8 af[4], bfr[4];
#pragma unroll
    for (int i = 0; i < 4; i++)
      af[i] = *(const bf16x8*)&As[(wm * 4 + i) * 512 + lane * 8];
#pragma unroll
    for (int j = 0; j < 4; j++)
      bfr[j] = *(const bf16x8*)&Bs[(wn * 4 + j) * 512 + lane * 8];
#pragma unroll
    for (int i = 0; i < 4; i++)
#pragma unroll
      for (int j = 0; j < 4; j++)
        acc[i][j] = __builtin_amdgcn_mfma_f32_16x16x32_bf16(af[i], bfr[j], acc[i][j], 0, 0, 0);
  }

#pragma unroll
  for (int i = 0; i < 4; i++) {
    int rbase = m0 + (wm * 4 + i) * 16 + q * 4;
#pragma unroll
    for (int r = 0; r < 4; r++) {
      int gm = rbase + r;
      if (gm >= M) continue;
#pragma unroll
      for (int j = 0; j < 4; j++) {
        float v = acc[i][j][r];
        if (relu) v = fmaxf(v, 0.f);
        int gn = col_off + n0 + (wn * 4 + j) * 16 + r16;
        if (out32)
          ((float*)Cv)[(size_t)gm * ldc + gn] = v;
        else
          ((unsigned short*)Cv)[(size_t)gm * ldc + gn] = f2bf(v);
      }
    }
  }
}

// fused conv1-GEMM (z=0: relu(aggX'@W1) -> cols 0..255) + fc-GEMM (z=1: xb@Wfc -> cols 256..511)
__global__ __launch_bounds__(256) void gemm12_kernel(
    const unsigned short* __restrict__ A0, const unsigned short* __restrict__ B0,
    const unsigned short* __restrict__ A1, const unsigned short* __restrict__ B1,
    unsigned short* __restrict__ C, int M) {
  __shared__ unsigned short As[8 * 512];
  __shared__ unsigned short Bs[8 * 512];
  int z = blockIdx.z;
  gemm_body(z ? A1 : A0, 128, z ? B1 : B0, 128, C, 512, z * 256, M, z == 0, 0, As, Bs);
}

__global__ __launch_bounds__(256) void gemm_kernel(
    const unsigned short* __restrict__ A, int lda,
    const unsigned short* __restrict__ Bt, int K,
    void* __restrict__ Cv, int ldc, int M, int relu, int out32) {
  __shared__ unsigned short As[8 * 512];
  __shared__ unsigned short Bs[8 * 512];
  gemm_body(A, lda, Bt, K, Cv, ldc, 0, M, relu, out32, As, Bs);
}

// ---------------- LayerNorm + relu (bf16 in/out, fp32 stats) ----------------
__global__ void ln_relu_bf16(unsigned short* __restrict__ h, int ld,
                             const float* __restrict__ gamma,
                             const float* __restrict__ beta) {
  int v = blockIdx.x;
  int f = threadIdx.x;  // 256
  float val = bf_lo((unsigned)h[(size_t)v * ld + f]);
  float s = val, qq = val * val;
#pragma unroll
  for (int off = 32; off > 0; off >>= 1) {
    s += __shfl_down(s, off);
    qq += __shfl_down(qq, off);
  }
  __shared__ float ws_[5], wq_[5];
  int wave = f >> 6, lane = f & 63;
  if (lane == 0) { ws_[wave] = s; wq_[wave] = qq; }
  __syncthreads();
  if (f == 0) {
    float S = 0, Q = 0;
    for (int i = 0; i < 4; i++) { S += ws_[i]; Q += wq_[i]; }
    ws_[4] = S; wq_[4] = Q;
  }
  __syncthreads();
  float mean = ws_[4] * (1.f / 256.f);
  float var = wq_[4] * (1.f / 256.f) - mean * mean;
  float y = (val - mean) * rsqrtf(var + EPSF) * gamma[f] + beta[f];
  h[(size_t)v * ld + f] = f2bf(y > 0.f ? y : 0.f);
}

// ---------------- per-graph readout (graph_ids sorted), x3 fp32 ----------------
__global__ void readout_kernel(const float* __restrict__ x3, const int* __restrict__ gid,
                               float* __restrict__ out, int n) {
  int g = blockIdx.x;
  int part = blockIdx.y;  // 8 parts
  int f = threadIdx.x;    // 256
  int lo = 0, hi = n;
  while (lo < hi) { int mid = (lo + hi) >> 1; if (gid[mid] < g) lo = mid + 1; else hi = mid; }
  int s = lo;
  lo = s; hi = n;
  while (lo < hi) { int mid = (lo + hi) >> 1; if (gid[mid] < g + 1) lo = mid + 1; else hi = mid; }
  int e = lo;
  int len = e - s;
  if (len <= 0) return;
  int chunk = (len + 7) / 8;
  int cs = s + part * chunk;
  int ce = cs + chunk; if (ce > e) ce = e;
  if (cs >= ce) return;
  float acc = 0.f;
  for (int v = cs; v < ce; v++) acc += x3[(size_t)v * 256 + f];
  atomicAdd(&out[g * 256 + f], acc);
}

// ---------------- launch ----------------

extern "C" void kernel_launch(void* const* d_in, const int* in_sizes, int n_in,
                              void* d_out, int out_size, void* d_ws, size_t ws_size,
                              hipStream_t stream) {
  const float* x     = (const float*)d_in[0];
  const float* w     = (const float*)d_in[1];
  const float* W1    = (const float*)d_in[2];
  const float* Wfc   = (const float*)d_in[3];
  const float* gamma = (const float*)d_in[4];
  const float* beta  = (const float*)d_in[5];
  const float* W2    = (const float*)d_in[6];
  const float* W3    = (const float*)d_in[7];
  const int*   src   = (const int*)d_in[8];
  const int*   dst   = (const int*)d_in[9];
  const int*   gid   = (const int*)d_in[10];
  float* out = (float*)d_out;

  const int N = NN, E = NE;

  char* p = (char*)d_ws;
  auto alloc = [&](size_t bytes) {
    char* r = p;
    p += (bytes + 255) & ~(size_t)255;
    return r;
  };
  int*   deg_out = (int*)alloc((size_t)N * 4);
  int*   deg_in  = (int*)alloc((size_t)N * 4);   // contiguous after deg_out (incl. pad)
  float* onorm   = (float*)alloc((size_t)N * 4);
  float* inorm   = (float*)alloc((size_t)N * 4);
  int*   row_ptr = (int*)alloc((size_t)(N + 1) * 4);
  int*   bsum    = (int*)alloc(256 * 4);
  int*   boff    = (int*)alloc(256 * 4);
  int*   rank    = (int*)alloc((size_t)E * 4);
  int*   col     = (int*)alloc((size_t)E * 4);
  float* wse     = (float*)alloc((size_t)E * 4);
  unsigned short* xb    = (unsigned short*)alloc((size_t)N * 128 * 2);
  unsigned short* aggX  = (unsigned short*)alloc((size_t)N * 128 * 2);
  unsigned short* x1f1  = (unsigned short*)alloc((size_t)N * 512 * 2);
  unsigned short* y2    = (unsigned short*)alloc((size_t)N * 256 * 2);
  unsigned short* x2    = (unsigned short*)alloc((size_t)N * 256 * 2);
  unsigned short* aggx2 = (unsigned short*)alloc((size_t)N * 256 * 2);
  unsigned short* W1t   = (unsigned short*)alloc((size_t)256 * 128 * 2);
  unsigned short* Wfct  = (unsigned short*)alloc((size_t)256 * 128 * 2);
  unsigned short* W2t   = (unsigned short*)alloc((size_t)256 * 512 * 2);
  unsigned short* W3t   = (unsigned short*)alloc((size_t)256 * 256 * 2);
  float* x3 = (float*)x1f1;  // x1f1 dead after y2 GEMM; reuse storage

  // deg_out..deg_in are contiguous (alloc pads both to 256B): one memset
  hipMemsetAsync(deg_out, 0, (size_t)((char*)onorm - (char*)deg_out), stream);
  hipMemsetAsync(out, 0, (size_t)NG * 256 * 4, stream);

  const int nbS = (N + 255) / 256;  // 196

  deg_rank_kernel<<<(E + 255) / 256, 256, 0, stream>>>(src, dst, deg_out, deg_in, rank, E);
  norms_kernel<<<nbS, 256, 0, stream>>>(deg_out, deg_in, onorm, inorm, N);
  scan1_kernel<<<nbS, 256, 0, stream>>>(deg_in, bsum, N);
  scan2_kernel<<<1, 256, 0, stream>>>(bsum, boff, nbS, row_ptr, N);
  scan3_kernel<<<nbS, 256, 0, stream>>>(deg_in, boff, row_ptr, N);
  fill_kernel<<<(E + 255) / 256, 256, 0, stream>>>(src, dst, w, onorm, inorm, row_ptr,
                                                   rank, col, wse, E);

  cvt_x_kernel<<<(N * 128 / 4 + 255) / 256, 256, 0, stream>>>(x, xb, N * 128 / 4);
  cvt_wt_all<<<1024, 256, 0, stream>>>(W1, Wfc, W2, W3, W1t, Wfct, W2t, W3t);

  dim3 ggrid((N + 127) / 128, 2);       // 391 x 2
  dim3 ggridz((N + 127) / 128, 2, 2);   // 391 x 2 x 2 (z: which GEMM)

  // aggX' = inorm (.) agg(xb (.) onorm)   [norms folded into wse]
  spmm_bf16<0, 1><<<N, 64, 0, stream>>>(xb, 128, row_ptr, col, wse, aggX, 128);
  // z=0: x1 = relu(aggX' @ W1) -> x1f1[:,0:256] ; z=1: f1pre = xb @ Wfc -> x1f1[:,256:512]
  gemm12_kernel<<<ggridz, 256, 0, stream>>>(aggX, W1t, xb, Wfct, x1f1, N);
  // f1 = relu(LN(f1pre)) in place
  ln_relu_bf16<<<N, 256, 0, stream>>>(x1f1 + 256, 512, gamma, beta);
  // y2 = x1f1 @ W2
  gemm_kernel<<<ggrid, 256, 0, stream>>>(x1f1, 512, W2t, 512, y2, 256, N, 0, 0);
  // x2 = relu(agg'(y2))
  spmm_bf16<1, 2><<<N, 64, 0, stream>>>(y2, 256, row_ptr, col, wse, x2, 256);
  // aggx2 = agg'(x2)
  spmm_bf16<0, 2><<<N, 64, 0, stream>>>(x2, 256, row_ptr, col, wse, aggx2, 256);
  // x3 = relu(aggx2 @ W3) fp32
  gemm_kernel<<<ggrid, 256, 0, stream>>>(aggx2, 256, W3t, 256, x3, 256, N, 1, 1);
  // readout
  readout_kernel<<<dim3(NG, 8), 256, 0, stream>>>(x3, gid, out, N);
}